// Round 1
// baseline (33.681 us; speedup 1.0000x reference)
//
#include <hip/hip_runtime.h>
#include <math.h>

#define SEQ 512
#define DM  512
#define DK  64
#define NH  8
#define SCALE 0.125f   // 1/sqrt(64)

// ---------------------------------------------------------------------------
// Kernel 1: Q/K/V projections + reduced W_O.
// Blocks 0..511: row s -> Q[s,:], K[s,:], V[s,:]  (x rows staged in LDS).
// Blocks 512..575: v = b-512 -> Wor[v,d] = sum_h W_O[h*64+v, d].
// ---------------------------------------------------------------------------
__global__ __launch_bounds__(256) void qkv_wor_kernel(
    const float* __restrict__ xq, const float* __restrict__ xk,
    const float* __restrict__ WQ, const float* __restrict__ WK,
    const float* __restrict__ WV, const float* __restrict__ WO,
    float* __restrict__ Q, float* __restrict__ K,
    float* __restrict__ V, float* __restrict__ Wor)
{
    const int b   = blockIdx.x;
    const int tid = threadIdx.x;

    if (b >= SEQ) {
        const int v = b - SEQ;
        for (int d = tid; d < DM; d += 256) {
            float acc = 0.f;
            #pragma unroll
            for (int h = 0; h < NH; ++h) acc += WO[(h*DK + v)*DM + d];
            Wor[v*DM + d] = acc;
        }
        return;
    }

    __shared__ float xq_s[DM], xk_s[DM];
    __shared__ float part_s[3][4][DK];

    for (int i = tid; i < DM; i += 256) {
        xq_s[i] = xq[b*DM + i];
        xk_s[i] = xk[b*DM + i];
    }
    __syncthreads();

    const int k    = tid & 63;
    const int part = tid >> 6;
    const int d0   = part * (DM/4);
    float aq = 0.f, ak = 0.f, av = 0.f;
    #pragma unroll 4
    for (int d = d0; d < d0 + DM/4; ++d) {
        const float xqv = xq_s[d], xkv = xk_s[d];
        aq += xqv * WQ[d*DK + k];   // lanes k=0..63 read 64 consecutive floats
        ak += xkv * WK[d*DK + k];
        av += xkv * WV[d*DK + k];
    }
    part_s[0][part][k] = aq;
    part_s[1][part][k] = ak;
    part_s[2][part][k] = av;
    __syncthreads();

    if (tid < 3*DK) {
        const int m  = tid >> 6;   // 0,1,2
        const int kk = tid & 63;
        const float s = part_s[m][0][kk] + part_s[m][1][kk]
                      + part_s[m][2][kk] + part_s[m][3][kk];
        float* dst = (m == 0) ? Q : (m == 1) ? K : V;
        dst[b*DK + kk] = s;
    }
}

// ---------------------------------------------------------------------------
// Kernel 2: per Q-row fused  scores -> softmax -> PV -> (head @ Wor).
// One block (256 thr, 4 waves) per row s.
// ---------------------------------------------------------------------------
__global__ __launch_bounds__(256) void attn_out_kernel(
    const float* __restrict__ Q, const float* __restrict__ K,
    const float* __restrict__ V, const float* __restrict__ Wor,
    const float* __restrict__ amask, float* __restrict__ out)
{
    const int srow = blockIdx.x;
    const int tid  = threadIdx.x;
    const int lane = tid & 63;
    const int wid  = tid >> 6;

    __shared__ __align__(16) float q_s[DK];
    __shared__ float p_s[SEQ];
    __shared__ float red_s[4];
    __shared__ float hpart_s[4][DK];
    __shared__ float head_s[DK];

    if (tid < DK) q_s[tid] = Q[srow*DK + tid];
    __syncthreads();

    // ---- scores: 2 per thread ----
    float sc[2];
    const float4* q4 = reinterpret_cast<const float4*>(q_s);
    #pragma unroll
    for (int i = 0; i < 2; ++i) {
        const int t = tid + i*256;
        const float4* k4 = reinterpret_cast<const float4*>(K + t*DK);
        float acc = 0.f;
        #pragma unroll
        for (int d = 0; d < DK/4; ++d) {
            const float4 kv = k4[d], qv = q4[d];
            acc += qv.x*kv.x + qv.y*kv.y + qv.z*kv.z + qv.w*kv.w;
        }
        acc *= SCALE;
        if (amask[t] == 0.f) acc = -INFINITY;
        sc[i] = acc;
    }

    // ---- block max ----
    float wm = fmaxf(sc[0], sc[1]);
    #pragma unroll
    for (int off = 32; off; off >>= 1) wm = fmaxf(wm, __shfl_xor(wm, off, 64));
    if (lane == 0) red_s[wid] = wm;
    __syncthreads();
    const float bmax = fmaxf(fmaxf(red_s[0], red_s[1]), fmaxf(red_s[2], red_s[3]));
    __syncthreads();   // red_s reused below

    // ---- exp + block sum ----
    const float p0 = __expf(sc[0] - bmax);
    const float p1 = __expf(sc[1] - bmax);
    p_s[tid]       = p0;
    p_s[tid + 256] = p1;
    float wsum = p0 + p1;
    #pragma unroll
    for (int off = 32; off; off >>= 1) wsum += __shfl_xor(wsum, off, 64);
    if (lane == 0) red_s[wid] = wsum;
    __syncthreads();
    const float inv_sum = 1.f / (red_s[0] + red_s[1] + red_s[2] + red_s[3]);

    // ---- PV: head[v] = sum_t p[t] * V[t,v] ----
    const int t0 = wid * (SEQ/4);
    float hacc = 0.f;
    for (int t = t0; t < t0 + SEQ/4; ++t)
        hacc += p_s[t] * V[t*DK + lane];   // lanes read 64 consecutive floats
    hpart_s[wid][lane] = hacc;
    __syncthreads();
    if (tid < DK)
        head_s[tid] = (hpart_s[0][tid] + hpart_s[1][tid]
                     + hpart_s[2][tid] + hpart_s[3][tid]) * inv_sum;
    __syncthreads();

    // ---- out[s,d] = sum_v head[v] * Wor[v,d] ----
    #pragma unroll
    for (int i = 0; i < 2; ++i) {
        const int d = tid + i*256;
        float acc = 0.f;
        #pragma unroll 8
        for (int vv = 0; vv < DK; ++vv)
            acc += head_s[vv] * Wor[vv*DM + d];
        out[srow*DM + d] = acc;
    }
}

extern "C" void kernel_launch(void* const* d_in, const int* in_sizes, int n_in,
                              void* d_out, int out_size, void* d_ws, size_t ws_size,
                              hipStream_t stream) {
    const float* xq    = (const float*)d_in[0];
    const float* xk    = (const float*)d_in[1];
    const float* amask = (const float*)d_in[2];
    const float* WQ    = (const float*)d_in[3];
    const float* WK    = (const float*)d_in[4];
    const float* WV    = (const float*)d_in[5];
    const float* WO    = (const float*)d_in[6];
    float* out = (float*)d_out;

    float* ws  = (float*)d_ws;
    float* Q   = ws;
    float* K   = ws + SEQ*DK;
    float* V   = ws + 2*SEQ*DK;
    float* Wor = ws + 3*SEQ*DK;   // 64 x 512; total ws use = 512 KiB

    qkv_wor_kernel<<<SEQ + DK, 256, 0, stream>>>(xq, xk, WQ, WK, WV, WO, Q, K, V, Wor);
    attn_out_kernel<<<SEQ, 256, 0, stream>>>(Q, K, V, Wor, amask, out);
}